// Round 5
// baseline (573.748 us; speedup 1.0000x reference)
//
#include <hip/hip_runtime.h>

// Problem: B=1, S=I=H=4096. All tensors fp32 (inputs AND outputs).
// d_in: x(4096), hidden(4096), w_ih(12288*4096), w_hh(12288*4096),
//       b_ih(12288), b_hh(12288)
// d_out (fp32): outputs(4096*4096) ++ new_hidden(4096)
//
// Closed form of the reference scan:
//   g = [gi; gh] (24576 fp32) via GEMV
//   r = sig(gi_r+gh_r); z = sig(gi_z+gh_z); n = tanh(gi_n + r*gh_n)
//   a[s] = relu((1-z)*h + z*n)[s]
//   prefix[t] = inclusive_scan(a)[t]
//   outputs[t,j]  = prefix[t] + hidden[(j-t-1) & 4095]
//   new_hidden[j] = prefix[4095] + hidden[j]

#define H4 4096
#define R3 12288  // 3*H

// ---------------- Kernel 1: GEMV, memcpy-shaped weight stream -------------
// Block = 16 rows = contiguous 256 KB slab. Step i: the 256 threads read the
// next contiguous 4 KB (exactly the m13 copy pattern). For wave w, lane l at
// step i = 4*r + k (r=row phase 0..15, k=col quarter 0..3):
//   global float4 idx = base + i*256 + tid  ->  row = 16*blk + r,
//   col_f4 = 256*k + 64*w + l  (same col set for every r!)
// So each wave preloads its 4 vector float4s vk[k] into registers and keeps
// 16 per-row accumulators in registers. No LDS in the hot loop.
__global__ __launch_bounds__(256, 6) void gemv_kernel(
    const float* __restrict__ x,
    const float* __restrict__ hidden,
    const float* __restrict__ w_ih,
    const float* __restrict__ w_hh,
    const float* __restrict__ b_ih,
    const float* __restrict__ b_hh,
    float* __restrict__ g) {
  const int block = blockIdx.x;
  const bool isX = (block < 768);
  const float* vec  = isX ? x    : hidden;
  const float* wmat = isX ? w_ih : w_hh;
  const float* bias = isX ? b_ih : b_hh;
  const int rowb = (isX ? block : block - 768) * 16;
  const int gbase = isX ? 0 : R3;

  const int tid = threadIdx.x;
  const int lane = tid & 63;
  const int wid = tid >> 6;

  // Preload this wave's 4 vector chunks (col quarters) into registers.
  const float4* vv = reinterpret_cast<const float4*>(vec);
  float4 vk[4];
#pragma unroll
  for (int k = 0; k < 4; ++k) vk[k] = vv[k * 256 + tid];

  const float4* wp =
      reinterpret_cast<const float4*>(wmat) + (size_t)rowb * 1024 + tid;

  float acc[16];
#pragma unroll
  for (int r = 0; r < 16; ++r) acc[r] = 0.f;

#pragma unroll
  for (int r = 0; r < 16; ++r) {
#pragma unroll
    for (int k = 0; k < 4; ++k) {
      const float4 wq = wp[(r * 4 + k) * 256];
      acc[r] = fmaf(wq.x, vk[k].x, acc[r]);
      acc[r] = fmaf(wq.y, vk[k].y, acc[r]);
      acc[r] = fmaf(wq.z, vk[k].z, acc[r]);
      acc[r] = fmaf(wq.w, vk[k].w, acc[r]);
    }
  }

  // 16 wave reductions -> lane 0, then cross-wave combine in LDS.
  __shared__ float red[64];
#pragma unroll
  for (int r = 0; r < 16; ++r) {
    float s = acc[r];
#pragma unroll
    for (int d = 32; d > 0; d >>= 1) s += __shfl_down(s, d, 64);
    if (lane == 0) red[wid * 16 + r] = s;
  }
  __syncthreads();
  if (tid < 16) {
    const float v = (red[tid] + red[16 + tid]) + (red[32 + tid] + red[48 + tid]);
    g[gbase + rowb + tid] = v + bias[rowb + tid];
  }
}

// -------- Kernel 2: GRU combine + block-wide inclusive scan (1 block) -----
__global__ __launch_bounds__(1024) void combine_scan_kernel(
    const float* __restrict__ hidden,
    const float* __restrict__ g,
    float* __restrict__ prefix,
    float* __restrict__ out_newh) {
  const int tid = threadIdx.x;

  const float4 gir = reinterpret_cast<const float4*>(g)[tid];
  const float4 giz = reinterpret_cast<const float4*>(g + H4)[tid];
  const float4 gin = reinterpret_cast<const float4*>(g + 2 * H4)[tid];
  const float4 ghr = reinterpret_cast<const float4*>(g + R3)[tid];
  const float4 ghz = reinterpret_cast<const float4*>(g + R3 + H4)[tid];
  const float4 ghn = reinterpret_cast<const float4*>(g + R3 + 2 * H4)[tid];
  const float4 h4v = reinterpret_cast<const float4*>(hidden)[tid];

  const float ir[4] = {gir.x, gir.y, gir.z, gir.w};
  const float iz[4] = {giz.x, giz.y, giz.z, giz.w};
  const float in_[4] = {gin.x, gin.y, gin.z, gin.w};
  const float hr[4] = {ghr.x, ghr.y, ghr.z, ghr.w};
  const float hz[4] = {ghz.x, ghz.y, ghz.z, ghz.w};
  const float hn[4] = {ghn.x, ghn.y, ghn.z, ghn.w};
  const float hh[4] = {h4v.x, h4v.y, h4v.z, h4v.w};

  float a[4];
#pragma unroll
  for (int k = 0; k < 4; ++k) {
    const float r = 1.f / (1.f + __expf(-(ir[k] + hr[k])));
    const float z = 1.f / (1.f + __expf(-(iz[k] + hz[k])));
    const float n = tanhf(in_[k] + r * hn[k]);
    const float b = (1.f - z) * hh[k] + z * n;
    a[k] = fmaxf(b, 0.f);
  }
  const float c0 = a[0], c1 = c0 + a[1], c2 = c1 + a[2], c3 = c2 + a[3];
  const float tsum = c3;

  const int lane = tid & 63, wid = tid >> 6;
  float v = tsum;
#pragma unroll
  for (int d = 1; d < 64; d <<= 1) {
    float o = __shfl_up(v, d, 64);
    if (lane >= d) v += o;
  }
  __shared__ float wsum[16];
  if (lane == 63) wsum[wid] = v;
  __syncthreads();
  if (tid < 16) {
    float w = wsum[tid];
#pragma unroll
    for (int d = 1; d < 16; d <<= 1) {
      float o = __shfl_up(w, d, 64);
      if (tid >= d) w += o;
    }
    wsum[tid] = w;
  }
  __syncthreads();

  const float excl = (wid ? wsum[wid - 1] : 0.f) + (v - tsum);
  float4 pr;
  pr.x = excl + c0; pr.y = excl + c1; pr.z = excl + c2; pr.w = excl + c3;
  reinterpret_cast<float4*>(prefix)[tid] = pr;

  const float total = wsum[15];
  float4 nh;
  nh.x = total + hh[0]; nh.y = total + hh[1];
  nh.z = total + hh[2]; nh.w = total + hh[3];
  reinterpret_cast<float4*>(out_newh)[tid] = nh;
}

// ------- Kernel 3: outputs[t,j] = prefix[t] + hidden[(j-t-1)&4095] --------
__global__ __launch_bounds__(256) void outputs_kernel(
    const float* __restrict__ prefix,
    const float* __restrict__ hidden,
    float* __restrict__ out) {
  const int b = blockIdx.x;
  const int t = b >> 1;
  const int j0 = (b & 1) * 2048 + threadIdx.x * 8;
  const float p = prefix[t];
  const int base = (j0 - t - 1) & 4095;

  float4 o0, o1;
  o0.x = p + hidden[base];
  o0.y = p + hidden[(base + 1) & 4095];
  o0.z = p + hidden[(base + 2) & 4095];
  o0.w = p + hidden[(base + 3) & 4095];
  o1.x = p + hidden[(base + 4) & 4095];
  o1.y = p + hidden[(base + 5) & 4095];
  o1.z = p + hidden[(base + 6) & 4095];
  o1.w = p + hidden[(base + 7) & 4095];

  float* dst = out + (size_t)t * H4 + j0;
  *reinterpret_cast<float4*>(dst)     = o0;
  *reinterpret_cast<float4*>(dst + 4) = o1;
}

extern "C" void kernel_launch(void* const* d_in, const int* in_sizes, int n_in,
                              void* d_out, int out_size, void* d_ws, size_t ws_size,
                              hipStream_t stream) {
  const float* x      = (const float*)d_in[0];
  const float* hidden = (const float*)d_in[1];
  const float* w_ih   = (const float*)d_in[2];
  const float* w_hh   = (const float*)d_in[3];
  const float* b_ih   = (const float*)d_in[4];
  const float* b_hh   = (const float*)d_in[5];
  float* out = (float*)d_out;

  float* ws     = (float*)d_ws;
  float* g      = ws;          // 24576 fp32
  float* prefix = ws + 24576;  // 4096 fp32

  // 24576 rows / 16 rows per block -> 1536 blocks, each a contiguous 256 KB
  // sequential weight stream.
  gemv_kernel<<<1536, 256, 0, stream>>>(x, hidden, w_ih, w_hh, b_ih, b_hh, g);
  combine_scan_kernel<<<1, 1024, 0, stream>>>(hidden, g, prefix,
                                              out + (size_t)H4 * H4);
  outputs_kernel<<<8192, 256, 0, stream>>>(prefix, hidden, out);
}